// Round 12
// baseline (159.245 us; speedup 1.0000x reference)
//
#include <hip/hip_runtime.h>

#define N_ROWS   500000
#define N_TERMS  64
#define N_OUT    4
#define CHUNK_R  32
#define NCHUNK   (N_ROWS / CHUNK_R)                  // 15625 exact, no tail
#define NB       512                                  // blocks = partial slots
#define GRAM_WAVES_TOTAL (NB * 4)                     // 2048 gram waves
#define F4_TOTAL (N_ROWS * (N_TERMS / 4))             // 8,000,000 float4
#define PART_STRIDE (N_TERMS * N_TERMS + N_TERMS * N_OUT)  // 4352
#define CHUNKS   8
#define PER_CHUNK (NB / CHUNKS)                       // 64
#define JACOBI_ITERS 20

typedef float f32x4   __attribute__((ext_vector_type(4)));
typedef short bf16x8  __attribute__((ext_vector_type(8)));

__device__ inline unsigned short f32_bf16(float f) {      // RNE f32 -> bf16 bits
  unsigned int u = __builtin_bit_cast(unsigned int, f);
  u += 0x7fffu + ((u >> 16) & 1u);
  return (unsigned short)(u >> 16);
}

// 8-deep column fragment as bf16x8; LDS tile [32][64] fp32 with bit-4 column
// XOR swizzle per 8-row group (R7-validated construction).
__device__ inline bf16x8 frag_col(const float* __restrict__ Tf, int cswz, int k0) {
  bf16x8 r;
#pragma unroll
  for (int j = 0; j < 8; ++j)
    r[j] = (short)f32_bf16(Tf[(k0 + j) * 64 + cswz]);
  return r;
}

// K1: producer/consumer wave specialization.
//  waves 4..7: pure streaming copy theta -> out (no LDS, no barriers).
//  waves 0..3: Gram+Xty via wave-private LDS + MFMA, loads only (no stores
//              until the epilogue) so their vmcnt waits never serialize on
//              the HBM write drain.
__global__ __launch_bounds__(512, 4) void k1_gram(const float* __restrict__ th,
                                                  const float* __restrict__ td,
                                                  float* __restrict__ out_copy,
                                                  float* __restrict__ part) {
  __shared__ float4 W4[4 * 544];   // 4 gram waves x (512 f4 tile + 32 f4 y) = 34 KB

  const int tid  = threadIdx.x;
  const int wv   = tid >> 6;
  const int lane = tid & 63;
  const int g    = lane >> 4;            // k-slice group
  const int l15  = lane & 15;
  const int kg   = g * 8;                // fragment k offset
  const int szf  = (g & 1) << 4;         // fragment column swizzle

  const float4* th4 = (const float4*)th;
  const float4* td4 = (const float4*)td;
  float4* out4 = (float4*)out_copy;

  f32x4 c00 = {0.f,0.f,0.f,0.f}, c01 = c00, c02 = c00, c03 = c00;
  f32x4 c11 = c00, c12 = c00, c13 = c00, c22 = c00, c23 = c00, c33 = c00;
  float accY[4] = {0.f, 0.f, 0.f, 0.f};

  if (wv >= 4) {
    // ---------------- copy waves: pure stream ----------------
    const int cwid = blockIdx.x * 4 + (wv - 4);        // 0..2047
#pragma unroll 1
    for (int it = 0; it < 8; ++it) {
      const int base = it * (2048 * 512) + cwid * 512 + lane;
      float4 v[8];
#pragma unroll
      for (int u = 0; u < 8; ++u) {
        const int idx = base + u * 64;
        v[u] = (idx < F4_TOTAL) ? th4[idx] : make_float4(0.f, 0.f, 0.f, 0.f);
      }
#pragma unroll
      for (int u = 0; u < 8; ++u) {
        const int idx = base + u * 64;
        if (idx < F4_TOTAL) out4[idx] = v[u];
      }
    }
  } else {
    // ---------------- gram waves: loads only ----------------
    float4* Wt = W4 + wv * 544;          // wave-private tile (512 f4)
    float4* Wy = Wt + 512;               // wave-private y (32 f4)
    const float* Tf = (const float*)Wt;

    int ch = blockIdx.x * 4 + wv;        // chunk index, stride 2048
    float4 cur[8], yv;
    if (ch < NCHUNK) {
      const float4* src = th4 + (size_t)ch * 512;
#pragma unroll
      for (int j = 0; j < 8; ++j) cur[j] = src[j * 64 + lane];
      yv = make_float4(0.f, 0.f, 0.f, 0.f);
      if (lane < 32) yv = td4[(size_t)ch * CHUNK_R + lane];
    }

    while (ch < NCHUNK) {
      // stage into private LDS (swizzled, R7-validated)
#pragma unroll
      for (int j = 0; j < 8; ++j) {
        const int fi  = j * 64 + lane;
        const int swz = ((fi >> 7) & 1) << 2;
        Wt[(fi & ~15) | ((fi & 15) ^ swz)] = cur[j];
      }
      if (lane < 32) Wy[lane] = yv;

      // prefetch next chunk (loads overlap MFMA below)
      const int chn = ch + GRAM_WAVES_TOTAL;
      float4 nxt[8], ynxt;
      if (chn < NCHUNK) {
        const float4* srcn = th4 + (size_t)chn * 512;
#pragma unroll
        for (int j = 0; j < 8; ++j) nxt[j] = srcn[j * 64 + lane];
        ynxt = make_float4(0.f, 0.f, 0.f, 0.f);
        if (lane < 32) ynxt = td4[(size_t)chn * CHUNK_R + lane];
      }

      // fragments + upper-triangle Gram (R7-validated math)
      bf16x8 fr[4];
#pragma unroll
      for (int i = 0; i < 4; ++i)
        fr[i] = frag_col(Tf, (16 * i + l15) ^ szf, kg);

      c00 = __builtin_amdgcn_mfma_f32_16x16x32_bf16(fr[0], fr[0], c00, 0, 0, 0);
      c01 = __builtin_amdgcn_mfma_f32_16x16x32_bf16(fr[0], fr[1], c01, 0, 0, 0);
      c02 = __builtin_amdgcn_mfma_f32_16x16x32_bf16(fr[0], fr[2], c02, 0, 0, 0);
      c03 = __builtin_amdgcn_mfma_f32_16x16x32_bf16(fr[0], fr[3], c03, 0, 0, 0);
      c11 = __builtin_amdgcn_mfma_f32_16x16x32_bf16(fr[1], fr[1], c11, 0, 0, 0);
      c12 = __builtin_amdgcn_mfma_f32_16x16x32_bf16(fr[1], fr[2], c12, 0, 0, 0);
      c13 = __builtin_amdgcn_mfma_f32_16x16x32_bf16(fr[1], fr[3], c13, 0, 0, 0);
      c22 = __builtin_amdgcn_mfma_f32_16x16x32_bf16(fr[2], fr[2], c22, 0, 0, 0);
      c23 = __builtin_amdgcn_mfma_f32_16x16x32_bf16(fr[2], fr[3], c23, 0, 0, 0);
      c33 = __builtin_amdgcn_mfma_f32_16x16x32_bf16(fr[3], fr[3], c33, 0, 0, 0);

      // Xty fp32: lane = column, uniform-address y broadcast (R7-validated)
#pragma unroll
      for (int r = 0; r < CHUNK_R; ++r) {
        const int sz = ((r >> 3) & 1) << 4;
        const float  tv = Tf[r * 64 + (lane ^ sz)];
        const float4 yr = Wy[r];
        accY[0] += tv * yr.x;
        accY[1] += tv * yr.y;
        accY[2] += tv * yr.z;
        accY[3] += tv * yr.w;
      }

      ch = chn;
      if (ch < NCHUNK) {
#pragma unroll
        for (int j = 0; j < 8; ++j) cur[j] = nxt[j];
        yv = ynxt;
      }
    }
  }

  // ---- epilogue (only barriers in the kernel; copy waves just sync) ----
  __syncthreads();
  float* red  = (float*)W4;               // 64x65 padded Gram accumulator
  float* yred = red + 64 * 65;            // 256 floats

  for (int w = 0; w < 4; ++w) {
    if (wv == w) {
      const bool first = (w == 0);
      // C/D layout (R5-validated): in 16x16 tile (A,B): row=16A+4g+reg, col=16B+l15
#define WR_TILE(A, B, C)                                                    \
  {                                                                         \
    _Pragma("unroll") for (int r = 0; r < 4; ++r) {                         \
      const int e = (16 * (A) + 4 * g + r) * 65 + 16 * (B) + l15;           \
      if (first) red[e] = (C)[r]; else red[e] += (C)[r];                    \
    }                                                                       \
  }
#define WR_TILE_T(A, B, C)                                                  \
  {                                                                         \
    _Pragma("unroll") for (int r = 0; r < 4; ++r) {                         \
      const int e = (16 * (B) + l15) * 65 + 16 * (A) + 4 * g + r;           \
      if (first) red[e] = (C)[r]; else red[e] += (C)[r];                    \
    }                                                                       \
  }
      WR_TILE(0, 0, c00);
      WR_TILE(0, 1, c01); WR_TILE_T(0, 1, c01);
      WR_TILE(0, 2, c02); WR_TILE_T(0, 2, c02);
      WR_TILE(0, 3, c03); WR_TILE_T(0, 3, c03);
      WR_TILE(1, 1, c11);
      WR_TILE(1, 2, c12); WR_TILE_T(1, 2, c12);
      WR_TILE(1, 3, c13); WR_TILE_T(1, 3, c13);
      WR_TILE(2, 2, c22);
      WR_TILE(2, 3, c23); WR_TILE_T(2, 3, c23);
      WR_TILE(3, 3, c33);
#undef WR_TILE
#undef WR_TILE_T
      if (g == 0) {
        // lane l15 owns... (kept identical to R7: all lanes, lane=column)
      }
#pragma unroll
      for (int o = 0; o < 4; ++o) {
        const int e = lane * 4 + o;       // lane = column
        if (first) yred[e] = accY[o]; else yred[e] += accY[o];
      }
    }
    __syncthreads();
  }

  float* p = part + blockIdx.x * PART_STRIDE;
#pragma unroll
  for (int s = 0; s < 8; ++s) {
    const int e = s * 512 + tid;
    p[e] = red[(e >> 6) * 65 + (e & 63)];
  }
  if (tid < 256) p[4096 + tid] = yred[tid];
}

// K2a: 512 partials -> 8 chunk sums (fixed order)
__global__ __launch_bounds__(256) void k2a_reduce(const float* __restrict__ part,
                                                  float* __restrict__ mid) {
  const int eblk = blockIdx.x % 17;
  const int bch  = blockIdx.x / 17;
  const int e = eblk * 256 + threadIdx.x;
  if (e >= PART_STRIDE) return;
  const float* base = part + (size_t)bch * PER_CHUNK * PART_STRIDE + e;
  float s = 0.f;
  for (int i = 0; i < PER_CHUNK; ++i) s += base[i * PART_STRIDE];
  mid[bch * PART_STRIDE + e] = s;
}

// K3: final reduce (8 chunks) + Jacobi solve of XtX * coeffs = Xty.
// XtX ~ N*(I+E), rho(E)~0.023 -> 20 Jacobi iters >> fp32 noise.
__global__ __launch_bounds__(256) void k3_solve(const float* __restrict__ mid,
                                                float* __restrict__ coef_out) {
  __shared__ float A[64 * 65];
  __shared__ float bX[64 * 4];
  __shared__ float X0[64 * 4];
  __shared__ float X1[64 * 4];
  const int tid = threadIdx.x;

#pragma unroll
  for (int s = 0; s < 17; ++s) {
    const int e = s * 256 + tid;
    if (e < PART_STRIDE) {
      float v = 0.f;
#pragma unroll
      for (int c = 0; c < CHUNKS; ++c) v += mid[c * PART_STRIDE + e];
      if (e < 4096) A[(e >> 6) * 65 + (e & 63)] = v;
      else          bX[e - 4096] = v;
    }
  }
  __syncthreads();

  const int i = tid >> 2;
  const int c = tid & 3;

  float arow[64];
#pragma unroll
  for (int j = 0; j < 64; ++j) arow[j] = A[i * 65 + j];

  const float dinv = 1.0f / A[i * 65 + i];   // LDS read: keeps arow[] in registers
  const float b = bX[i * 4 + c];

  float x0 = b * dinv;
  X0[tid] = x0;
  __syncthreads();

  float xlast = x0;
  for (int it = 0; it < JACOBI_ITERS; ++it) {
    const float* Xr = (it & 1) ? X1 : X0;
    float*       Xw = (it & 1) ? X0 : X1;
    float s0 = 0.f, s1 = 0.f, s2 = 0.f, s3 = 0.f;
#pragma unroll
    for (int j = 0; j < 64; j += 4) {
      s0 += arow[j]     * Xr[(j)     * 4 + c];
      s1 += arow[j + 1] * Xr[(j + 1) * 4 + c];
      s2 += arow[j + 2] * Xr[(j + 2) * 4 + c];
      s3 += arow[j + 3] * Xr[(j + 3) * 4 + c];
    }
    const float s = (s0 + s1) + (s2 + s3);
    xlast = xlast + (b - s) * dinv;
    Xw[tid] = xlast;
    __syncthreads();
  }

  coef_out[tid] = xlast;
}

extern "C" void kernel_launch(void* const* d_in, const int* in_sizes, int n_in,
                              void* d_out, int out_size, void* d_ws, size_t ws_size,
                              hipStream_t stream) {
  const float* th = (const float*)d_in[0];   // [500000, 64] fp32
  const float* td = (const float*)d_in[1];   // [500000, 4]  fp32
  float* out = (float*)d_out;                // [32,000,000 copy | 256 coeffs]
  float* ws  = (float*)d_ws;

  float* part = ws;                                  // NB * 4352 floats
  float* mid  = ws + (size_t)NB * PART_STRIDE;       // CHUNKS * 4352
  // ws use: (512+8)*4352*4 B ~= 9.1 MB (proven footprint)

  hipLaunchKernelGGL(k1_gram, dim3(NB), dim3(512), 0, stream, th, td, out, part);
  hipLaunchKernelGGL(k2a_reduce, dim3(17 * CHUNKS), dim3(256), 0, stream, part, mid);
  hipLaunchKernelGGL(k3_solve, dim3(1), dim3(256), 0, stream, mid,
                     out + (size_t)N_ROWS * N_TERMS);
}